// Round 1
// baseline (214.384 us; speedup 1.0000x reference)
//
#include <hip/hip_runtime.h>

// NewSupConLoss: B=512, L=20, D=128. Loss via N=10240 Gram matrix, fused exp/reduce.
// ws layout: [0, 2621440) Fswz (bf16, swizzled rows a=l*512+i); then S[20][512] f32; then W[512] f32.

#define NB 512
#define NL 20
#define ND 128
#define NROW (NB * NL)            // 10240
#define FSWZ_BYTES (NROW * 256)   // 2,621,440
#define TEMP_INV 14.285714285714286f
#define C_EXP2 20.60992915555662f // log2(e)/0.07

typedef float f32x4 __attribute__((ext_vector_type(4)));
typedef short short8 __attribute__((ext_vector_type(8)));
typedef unsigned short ushort4v __attribute__((ext_vector_type(4)));

static __device__ __forceinline__ unsigned short f2bf(float x) {
  unsigned int b = __float_as_uint(x);
  b += 0x7FFFu + ((b >> 16) & 1u);  // round-to-nearest-even
  return (unsigned short)(b >> 16);
}

// Kernel 0: fp32 [B,L,D] -> bf16 rows a=l*512+i, XOR-swizzled within each 256B row.
// Also zeroes S (10240 f32) + W (512 f32) = 10752 floats.
__global__ __launch_bounds__(256) void k_convert(const float* __restrict__ feat,
                                                 unsigned char* __restrict__ fswz,
                                                 float* __restrict__ zbuf) {
  int t = blockIdx.x * 256 + threadIdx.x;   // [0, 327680)
  if (t < 10752) zbuf[t] = 0.f;
  int q = t & 31;          // float4 index within row (32 per row)
  int a = t >> 5;          // row 0..10239
  int l = a >> 9;
  int i = a & 511;
  const float* src = feat + (size_t)i * (NL * ND) + l * ND + q * 4;
  float4 v = *(const float4*)src;
  ushort4v u;
  u.x = f2bf(v.x); u.y = f2bf(v.y); u.z = f2bf(v.z); u.w = f2bf(v.w);
  int dst = a * 256 + ((q * 8) ^ ((a & 7) << 4));  // swizzle baked into global layout
  *(ushort4v*)(fswz + dst) = u;
}

// Kernel 1: fused Gram + exp + reductions. Grid (80,80): ta = A row-tile, tb = B row-tile.
// Tile rows: l = ta>>2, i in [(ta&3)*128, +128). Cols: c = tb>>2, j in [(tb&3)*128, +128).
__global__ __launch_bounds__(256) void k_gram(const unsigned char* __restrict__ fswz,
                                              const int* __restrict__ labels,
                                              float* __restrict__ S,
                                              float* __restrict__ W) {
  __shared__ unsigned char lds[65536];  // A tile 32KB @0, B tile 32KB @32768
  const int ta = blockIdx.x, tb = blockIdx.y;
  const int tid = threadIdx.x;
  const int lane = tid & 63, w = tid >> 6;

  // ---- stage: linear copy (source pre-swizzled) via global_load_lds width 16 ----
  const unsigned char* gA = fswz + (size_t)ta * 32768 + w * 8192 + lane * 16;
  const unsigned char* gB = fswz + (size_t)tb * 32768 + w * 8192 + lane * 16;
  unsigned char* lA = lds + w * 8192;
  unsigned char* lB = lds + 32768 + w * 8192;
#pragma unroll
  for (int t = 0; t < 8; ++t) {
    __builtin_amdgcn_global_load_lds(
        (const __attribute__((address_space(1))) unsigned int*)(gA + t * 1024),
        (__attribute__((address_space(3))) unsigned int*)(lA + t * 1024), 16, 0, 0);
    __builtin_amdgcn_global_load_lds(
        (const __attribute__((address_space(1))) unsigned int*)(gB + t * 1024),
        (__attribute__((address_space(3))) unsigned int*)(lB + t * 1024), 16, 0, 0);
  }
  __syncthreads();

  // ---- MFMA: wave (wr,wc) owns a 64x64 quadrant; 4x4 frags of 16x16x32 ----
  const int fr = lane & 15;
  const int kg = lane >> 4;
  const int wr = (w >> 1) * 64;
  const int wc = (w & 1) * 64;
  const int xr = (fr & 7) << 4;   // row-swizzle XOR (row%8 == fr%8 for all frag rows)
  f32x4 acc[4][4] = {};
#pragma unroll
  for (int kk = 0; kk < 4; ++kk) {
    const int kb = kk * 64 + kg * 16;   // byte offset of this lane's 8 bf16 in K
    short8 af[4], bf[4];
#pragma unroll
    for (int m = 0; m < 4; ++m) {
      int r = wr + m * 16 + fr;
      af[m] = *(const short8*)(lds + r * 256 + (kb ^ xr));
    }
#pragma unroll
    for (int n = 0; n < 4; ++n) {
      int r = wc + n * 16 + fr;
      bf[n] = *(const short8*)(lds + 32768 + r * 256 + (kb ^ xr));
    }
#pragma unroll
    for (int m = 0; m < 4; ++m)
#pragma unroll
      for (int n = 0; n < 4; ++n)
        acc[m][n] = __builtin_amdgcn_mfma_f32_16x16x32_bf16(af[m], bf[n], acc[m][n], 0, 0, 0);
  }

  // ---- epilogue: exp + row reduce + atomics ----
  const int c = tb >> 2;
  const int i0 = (ta & 3) * 128, j0 = (tb & 3) * 128;
  const bool sameIJ = ((ta & 3) == (tb & 3));
  const bool sameLC = ((ta >> 2) == c);
  float labj[4];
  if (sameLC) {
#pragma unroll
    for (int n = 0; n < 4; ++n)
      labj[n] = (float)labels[(j0 + wc + n * 16 + fr) * NL + c];
  }
  float* Srow = S + c * NB + i0;
#pragma unroll
  for (int m = 0; m < 4; ++m) {
#pragma unroll
    for (int reg = 0; reg < 4; ++reg) {
      const int row_l = wr + m * 16 + kg * 4 + reg;   // C/D: row=(lane>>4)*4+reg
      float esum = 0.f, wsum = 0.f;
#pragma unroll
      for (int n = 0; n < 4; ++n) {
        float g = acc[m][n][reg];
        int col_l = wc + n * 16 + fr;                 // C/D: col=lane&15
        bool dg = sameIJ && (row_l == col_l);
        esum += dg ? 0.f : exp2f(g * C_EXP2);
        if (sameLC) wsum += dg ? 0.f : g * labj[n];
      }
#pragma unroll
      for (int s = 1; s < 16; s <<= 1) esum += __shfl_xor(esum, s, 64);
      if (sameLC) {
#pragma unroll
        for (int s = 1; s < 16; s <<= 1) wsum += __shfl_xor(wsum, s, 64);
      }
      if (fr == 0) {
        atomicAdd(Srow + row_l, esum);
        if (sameLC) {
          int gi = i0 + row_l;
          if (labels[gi * NL + c] != 0 && wsum != 0.f)
            atomicAdd(W + gi, wsum * TEMP_INV);
        }
      }
    }
  }
}

// Kernel 2: per-anchor combine + mean. One block, 512 threads (thread i = anchor i).
__global__ __launch_bounds__(512) void k_final(const float* __restrict__ S,
                                               const float* __restrict__ W,
                                               const int* __restrict__ labels,
                                               float* __restrict__ out) {
  __shared__ float cnt[NL];
  __shared__ float red[8];
  const int i = threadIdx.x;
  if (i < NL) cnt[i] = 0.f;
  __syncthreads();
  int lab[NL];
#pragma unroll
  for (int cI = 0; cI < NL; ++cI) lab[cI] = labels[i * NL + cI];
#pragma unroll
  for (int cI = 0; cI < NL; ++cI)
    if (lab[cI]) atomicAdd(&cnt[cI], 1.f);
  __syncthreads();
  float avg = 0.f, ls = 0.f;
#pragma unroll
  for (int cI = 0; cI < NL; ++cI) {
    if (lab[cI]) {
      float wgt = cnt[cI] - 1.f;   // sum_{j!=i} lab[c,j]
      avg += wgt;
      ls += wgt * logf(S[cI * NB + i]);
    }
  }
  float v = (W[i] - ls) / (avg == 0.f ? 1.f : avg);
#pragma unroll
  for (int s = 1; s < 64; s <<= 1) v += __shfl_xor(v, s, 64);
  if ((i & 63) == 0) red[i >> 6] = v;
  __syncthreads();
  if (i == 0) {
    float tot = 0.f;
#pragma unroll
    for (int k = 0; k < 8; ++k) tot += red[k];
    out[0] = -(tot / (float)NB);   // TEMP/BASE_TEMP == 1
  }
}

extern "C" void kernel_launch(void* const* d_in, const int* in_sizes, int n_in,
                              void* d_out, int out_size, void* d_ws, size_t ws_size,
                              hipStream_t stream) {
  const float* feat = (const float*)d_in[0];
  const int* labels = (const int*)d_in[1];
  float* out = (float*)d_out;
  unsigned char* ws = (unsigned char*)d_ws;
  unsigned char* fswz = ws;
  float* S = (float*)(ws + FSWZ_BYTES);
  float* W = S + NL * NB;

  k_convert<<<NROW * 32 / 256, 256, 0, stream>>>(feat, fswz, S);  // also zeroes S+W
  dim3 grid(80, 80);
  k_gram<<<grid, 256, 0, stream>>>(fswz, labels, S, W);
  k_final<<<1, 512, 0, stream>>>(S, W, labels, out);
}

// Round 2
// 83.974 us; speedup vs baseline: 2.5530x; 2.5530x over previous
//
#include <hip/hip_runtime.h>

// NewSupConLoss: B=512, L=20, D=128. Gram N=10240, fused exp/reduce.
// Round 2: persistent-A streaming blocks. Grid (80 ta, 10 g): block = 128-row
// strip x 1024 cols (8 B-tiles = 2 classes), B double-buffered in LDS.
// Features pre-scaled by sqrt(log2(e)/T) so dot feeds v_exp_f32 directly.

#define NB 512
#define NL 20
#define ND 128
#define NROW (NB * NL)            // 10240
#define FSWZ_BYTES (NROW * 256)   // 2,621,440
#define SCALE 4.5398160f          // sqrt(log2(e)/0.07)
#define LN2 0.69314718056f        // (T*C_EXP2)^-1 = ln2 : converts scaled dot -> dot/T

typedef float f32x4 __attribute__((ext_vector_type(4)));
typedef short short8 __attribute__((ext_vector_type(8)));
typedef unsigned short ushort4v __attribute__((ext_vector_type(4)));

static __device__ __forceinline__ unsigned short f2bf(float x) {
  unsigned int b = __float_as_uint(x);
  b += 0x7FFFu + ((b >> 16) & 1u);
  return (unsigned short)(b >> 16);
}

static __device__ __forceinline__ float fexp2(float x) {
#if __has_builtin(__builtin_amdgcn_exp2f)
  return __builtin_amdgcn_exp2f(x);
#else
  return exp2f(x);
#endif
}

// fp32 [B,L,D] -> bf16 rows a=l*512+i, scaled by SCALE, XOR-swizzled per 256B row.
// Also zeroes S (10240 f32) + W (512 f32).
__global__ __launch_bounds__(256) void k_convert(const float* __restrict__ feat,
                                                 unsigned char* __restrict__ fswz,
                                                 float* __restrict__ zbuf) {
  int t = blockIdx.x * 256 + threadIdx.x;   // [0, 327680)
  if (t < 10752) zbuf[t] = 0.f;
  int q = t & 31;
  int a = t >> 5;
  int l = a >> 9;
  int i = a & 511;
  const float* src = feat + (size_t)i * (NL * ND) + l * ND + q * 4;
  float4 v = *(const float4*)src;
  ushort4v u;
  u.x = f2bf(v.x * SCALE); u.y = f2bf(v.y * SCALE);
  u.z = f2bf(v.z * SCALE); u.w = f2bf(v.w * SCALE);
  int dst = a * 256 + ((q * 8) ^ ((a & 7) << 4));
  *(ushort4v*)(fswz + dst) = u;
}

__global__ __launch_bounds__(256, 2) void k_gram(const unsigned char* __restrict__ fswz,
                                                 const int* __restrict__ labels,
                                                 float* __restrict__ S,
                                                 float* __restrict__ W) {
  __shared__ unsigned char lds[65536];   // two 32KB B buffers
  const int ta = blockIdx.x;             // row strip [ta*128, +128)
  const int g = blockIdx.y;              // col group: tb in [8g, 8g+8)
  const int tid = threadIdx.x;
  const int lane = tid & 63, w = tid >> 6;
  const int fr = lane & 15, kg = lane >> 4;
  const int wr = (w >> 1) * 64, wc = (w & 1) * 64;
  const int xr = (fr & 7) << 4;
  const int l = ta >> 2;

  // ---- persistent A fragments: 16 x short8 = 64 VGPR ----
  short8 af[4][4];   // [kk][m]
#pragma unroll
  for (int kk = 0; kk < 4; ++kk)
#pragma unroll
    for (int m = 0; m < 4; ++m) {
      int row = ta * 128 + wr + m * 16 + fr;
      af[kk][m] = *(const short8*)(fswz + row * 256 + ((kk * 64 + kg * 16) ^ xr));
    }

  const int tb0 = g * 8;
  auto stage = [&](int buf, int tb) {
    const unsigned char* gB = fswz + (size_t)tb * 32768 + w * 8192 + lane * 16;
    unsigned char* lB = lds + buf * 32768 + w * 8192;   // wave-uniform LDS base
#pragma unroll
    for (int tt = 0; tt < 8; ++tt)
      __builtin_amdgcn_global_load_lds(
          (const __attribute__((address_space(1))) unsigned int*)(gB + tt * 1024),
          (__attribute__((address_space(3))) unsigned int*)(lB + tt * 1024), 16, 0, 0);
  };

  stage(0, tb0);
  __syncthreads();   // drains vmcnt(0): buf0 ready

  float esum[4][4] = {};   // [m][reg], per current class c
  float wsum[4][4] = {};
  int cur = 0;

#pragma unroll
  for (int t = 0; t < 8; ++t) {
    const int tb = tb0 + t;
    if (t < 7) stage(cur ^ 1, tb + 1);   // issue next-tile loads early

    // ---- B frags + MFMA ----
    const unsigned char* lb = lds + cur * 32768;
    f32x4 acc[4][4] = {};
#pragma unroll
    for (int kk = 0; kk < 4; ++kk) {
      short8 bf[4];
#pragma unroll
      for (int n = 0; n < 4; ++n) {
        int rb = wc + n * 16 + fr;
        bf[n] = *(const short8*)(lb + rb * 256 + ((kk * 64 + kg * 16) ^ xr));
      }
#pragma unroll
      for (int m = 0; m < 4; ++m)
#pragma unroll
        for (int n = 0; n < 4; ++n)
          acc[m][n] = __builtin_amdgcn_mfma_f32_16x16x32_bf16(af[kk][m], bf[n], acc[m][n], 0, 0, 0);
    }

    // ---- epilogue: exp + register accumulate ----
    const int c = tb >> 2;
    const bool maskstep = ((t & 3) == (ta & 3));   // tb&3 == ta&3 -> diag (i==j) possible
    const bool lc = (c == l);

#define EPI(MASKED)                                                         \
  _Pragma("unroll") for (int m = 0; m < 4; ++m)                             \
  _Pragma("unroll") for (int reg = 0; reg < 4; ++reg) {                     \
    const int row_l = wr + m * 16 + kg * 4 + reg;                           \
    float e = 0.f;                                                          \
    _Pragma("unroll") for (int n = 0; n < 4; ++n) {                         \
      float ex = fexp2(acc[m][n][reg]);                                     \
      if (MASKED && row_l == (wc + n * 16 + fr)) ex = 0.f;                  \
      e += ex;                                                              \
    }                                                                       \
    esum[m][reg] += e;                                                      \
  }
    if (maskstep) { EPI(1) } else { EPI(0) }
#undef EPI

    if (lc) {   // rare: numerator/W accumulation for this class strip
      float labj[4];
#pragma unroll
      for (int n = 0; n < 4; ++n)
        labj[n] = (float)labels[((tb * 128 + wc + n * 16 + fr) & 511) * NL + c];
#pragma unroll
      for (int m = 0; m < 4; ++m)
#pragma unroll
        for (int reg = 0; reg < 4; ++reg) {
          const int row_l = wr + m * 16 + kg * 4 + reg;
          float ws = 0.f;
#pragma unroll
          for (int n = 0; n < 4; ++n) {
            float gv = acc[m][n][reg];
            bool dg = maskstep && (row_l == (wc + n * 16 + fr));
            ws += dg ? 0.f : gv * labj[n];
          }
          wsum[m][reg] += ws;
        }
    }

    // ---- flush at class boundary (t=3,7): shfl-reduce + atomic ----
    if ((t & 3) == 3) {
#pragma unroll
      for (int m = 0; m < 4; ++m)
#pragma unroll
        for (int reg = 0; reg < 4; ++reg) {
          float e = esum[m][reg];
          e += __shfl_xor(e, 1, 64); e += __shfl_xor(e, 2, 64);
          e += __shfl_xor(e, 4, 64); e += __shfl_xor(e, 8, 64);
          float ww = 0.f;
          if (lc) {
            ww = wsum[m][reg];
            ww += __shfl_xor(ww, 1, 64); ww += __shfl_xor(ww, 2, 64);
            ww += __shfl_xor(ww, 4, 64); ww += __shfl_xor(ww, 8, 64);
          }
          if (fr == 0) {
            const int ia = (ta * 128 + wr + m * 16 + kg * 4 + reg) & 511;
            atomicAdd(S + c * NB + ia, e);
            if (lc && labels[ia * NL + c] != 0 && ww != 0.f)
              atomicAdd(W + ia, ww * LN2);
          }
          esum[m][reg] = 0.f;
          wsum[m][reg] = 0.f;
        }
    }

    __syncthreads();   // drains vmcnt(0): staged buf ready; LDS reads done
    cur ^= 1;
  }
}

// Per-anchor combine + mean. One block, 512 threads.
__global__ __launch_bounds__(512) void k_final(const float* __restrict__ S,
                                               const float* __restrict__ W,
                                               const int* __restrict__ labels,
                                               float* __restrict__ out) {
  __shared__ float cnt[NL];
  __shared__ float red[8];
  const int i = threadIdx.x;
  if (i < NL) cnt[i] = 0.f;
  __syncthreads();
  int lab[NL];
#pragma unroll
  for (int cI = 0; cI < NL; ++cI) lab[cI] = labels[i * NL + cI];
#pragma unroll
  for (int cI = 0; cI < NL; ++cI)
    if (lab[cI]) atomicAdd(&cnt[cI], 1.f);
  __syncthreads();
  float avg = 0.f, ls = 0.f;
#pragma unroll
  for (int cI = 0; cI < NL; ++cI) {
    if (lab[cI]) {
      float wgt = cnt[cI] - 1.f;
      avg += wgt;
      ls += wgt * logf(S[cI * NB + i]);
    }
  }
  float v = (W[i] - ls) / (avg == 0.f ? 1.f : avg);
#pragma unroll
  for (int s = 1; s < 64; s <<= 1) v += __shfl_xor(v, s, 64);
  if ((i & 63) == 0) red[i >> 6] = v;
  __syncthreads();
  if (i == 0) {
    float tot = 0.f;
#pragma unroll
    for (int k = 0; k < 8; ++k) tot += red[k];
    out[0] = -(tot / (float)NB);
  }
}

extern "C" void kernel_launch(void* const* d_in, const int* in_sizes, int n_in,
                              void* d_out, int out_size, void* d_ws, size_t ws_size,
                              hipStream_t stream) {
  const float* feat = (const float*)d_in[0];
  const int* labels = (const int*)d_in[1];
  float* out = (float*)d_out;
  unsigned char* ws = (unsigned char*)d_ws;
  unsigned char* fswz = ws;
  float* S = (float*)(ws + FSWZ_BYTES);
  float* W = S + NL * NB;

  k_convert<<<NROW * 32 / 256, 256, 0, stream>>>(feat, fswz, S);
  dim3 grid(80, 10);
  k_gram<<<grid, 256, 0, stream>>>(fswz, labels, S, W);
  k_final<<<1, 512, 0, stream>>>(S, W, labels, out);
}